// Round 8
// baseline (152.367 us; speedup 1.0000x reference)
//
#include <hip/hip_runtime.h>

#define S_LEN 4096
#define DMODEL 512
#define NHEADS 8
#define DHEAD 64

typedef unsigned short u16;
typedef unsigned int u32;
typedef __attribute__((ext_vector_type(8))) short bf16x8;
typedef __attribute__((ext_vector_type(4))) float f32x4;
typedef __attribute__((ext_vector_type(8))) float f32x8;
typedef __attribute__((ext_vector_type(16))) float f32x16;

#if __has_builtin(__builtin_amdgcn_exp2f)
#define EXP2(x) __builtin_amdgcn_exp2f(x)
#else
#define EXP2(x) exp2f(x)
#endif

__device__ __forceinline__ u16 f2b(float f) {
  unsigned u = __builtin_bit_cast(unsigned, f);
  return (u16)((u + 0x7fffu + ((u >> 16) & 1u)) >> 16);
}
__device__ __forceinline__ float fmax3(float a, float b, float c) {
  return fmaxf(fmaxf(a, b), c);
}

__device__ __forceinline__ f32x4 mfma16(bf16x8 a, bf16x8 b, f32x4 c) {
  return __builtin_amdgcn_mfma_f32_16x16x32_bf16(a, b, c, 0, 0, 0);
}
__device__ __forceinline__ f32x16 mfma32(bf16x8 a, bf16x8 b, f32x16 c) {
  return __builtin_amdgcn_mfma_f32_32x32x16_bf16(a, b, c, 0, 0, 0);
}

// pack two f32 -> one u32 of 2 bf16 (RNE), S0 -> low half
__device__ __forceinline__ u32 pkbf(float lo, float hi) {
  u32 r;
  asm("v_cvt_pk_bf16_f32 %0, %1, %2" : "=v"(r) : "v"(lo), "v"(hi));
  return r;
}

// swap a.hi32lanes <-> b.lo32lanes
__device__ __forceinline__ void plswap(u32& a, u32& b) {
#if __has_builtin(__builtin_amdgcn_permlane32_swap)
  auto r = __builtin_amdgcn_permlane32_swap(a, b, false, false);
  a = r[0];
  b = r[1];
#else
  u32 as = __shfl_xor((int)a, 32), bs = __shfl_xor((int)b, 32);
  bool hi = (threadIdx.x & 32) != 0;
  u32 na = hi ? bs : a;
  u32 nb = hi ? b : as;
  a = na;
  b = nb;
#endif
}
// cross-half (lane ^ 32) exchange of one value, both outputs
__device__ __forceinline__ void xhalf(float x, float& own, float& other) {
  u32 a = __builtin_bit_cast(u32, x), b = a;
  plswap(a, b);
  own = __builtin_bit_cast(float, a);
  other = __builtin_bit_cast(float, b);
}

// read a 16B MFMA fragment from an LDS tile with 128B rows, XOR chunk swizzle
__device__ __forceinline__ bf16x8 ldsfrag(const char* base, int row, int chunk) {
  chunk ^= (row & 7);
  return __builtin_bit_cast(bf16x8, *(const uint4*)(base + row * 128 + chunk * 16));
}

#define GLOAD16(gsrc, ldst) __builtin_amdgcn_global_load_lds( \
    (const __attribute__((address_space(1))) void*)(gsrc),    \
    (__attribute__((address_space(3))) void*)(ldst), 16, 0, 0)

// fp32 -> bf16: 4 weight tensors in one launch (each 65536 float4)
__global__ void cvt_w4(const float* __restrict__ a, const float* __restrict__ b,
                       const float* __restrict__ c, const float* __restrict__ d,
                       u16* __restrict__ oa, u16* __restrict__ ob,
                       u16* __restrict__ oc, u16* __restrict__ od) {
  int which = blockIdx.x >> 8;
  int i = (blockIdx.x & 255) * 256 + threadIdx.x;
  const float* src = which == 0 ? a : which == 1 ? b : which == 2 ? c : d;
  u16* dst = which == 0 ? oa : which == 1 ? ob : which == 2 ? oc : od;
  float4 v = ((const float4*)src)[i];
  ushort4 o;
  o.x = f2b(v.x); o.y = f2b(v.y); o.z = f2b(v.z); o.w = f2b(v.w);
  ((ushort4*)dst)[i] = o;
}

// fp32 -> bf16: 3 input tensors (each 1048576 float4) in one launch
__global__ void cvt_in3(const float* __restrict__ a, const float* __restrict__ b,
                        const float* __restrict__ c,
                        u16* __restrict__ oa, u16* __restrict__ ob, u16* __restrict__ oc) {
  int which = blockIdx.x >> 12;
  int i = (blockIdx.x & 4095) * 256 + threadIdx.x;
  const float* src = which == 0 ? a : which == 1 ? b : c;
  u16* dst = which == 0 ? oa : which == 1 ? ob : oc;
  float4 v = ((const float4*)src)[i];
  ushort4 o;
  o.x = f2b(v.x); o.y = f2b(v.y); o.z = f2b(v.z); o.w = f2b(v.w);
  ((ushort4*)dst)[i] = o;
}

// single fp32->bf16 (fallback path)
__global__ void cvt4(const float* __restrict__ in, u16* __restrict__ out, int n4) {
  int i = blockIdx.x * blockDim.x + threadIdx.x;
  if (i < n4) {
    float4 v = ((const float4*)in)[i];
    ushort4 o;
    o.x = f2b(v.x); o.y = f2b(v.y); o.z = f2b(v.z); o.w = f2b(v.w);
    ((ushort4*)out)[i] = o;
  }
}

// C = alpha * (X[M,K] @ W[N,K]^T + bias[N]);  X,W bf16, acc fp32.
// mode 0: bf16 out[((b*H+h)*S + s)*64 + dh]      (m=b*4096+s, n=h*64+dh)
// mode 1: bf16 out[((b*H+h)*64 + dh)*S + s]      (V transposed)
// mode 2: f32  out[m*N + n]
// blockIdx.z selects (X,W,bias,out,alpha); modesel==-1: mode = (z==2)?1:0,
// else mode = modesel.
__global__ __launch_bounds__(256) void gemm_xwt(
    const u16* __restrict__ X0, const u16* __restrict__ X1, const u16* __restrict__ X2,
    const u16* __restrict__ W0, const u16* __restrict__ W1, const u16* __restrict__ W2,
    const float* __restrict__ b0, const float* __restrict__ b1, const float* __restrict__ b2,
    void* __restrict__ o0, void* __restrict__ o1, void* __restrict__ o2,
    float alpha0, float alpha1, float alpha2, int modesel) {
  constexpr int K = 512, N = 512;
  __shared__ char smem[34816];
  const int z = blockIdx.z;
  const u16* X = z == 0 ? X0 : z == 1 ? X1 : X2;
  const u16* W = z == 0 ? W0 : z == 1 ? W1 : W2;
  const float* bias = z == 0 ? b0 : z == 1 ? b1 : b2;
  void* outp = z == 0 ? o0 : z == 1 ? o1 : o2;
  const float alpha = z == 0 ? alpha0 : z == 1 ? alpha1 : alpha2;
  const int mode = modesel >= 0 ? modesel : (z == 2 ? 1 : 0);

  const int t = threadIdx.x;
  const int w = t >> 6, l = t & 63;
  const int wm = w >> 1, wn = w & 1;
  const int m0 = blockIdx.y * 128, n0 = blockIdx.x * 128;
  const int srow = t >> 3, sch = t & 7;

  f32x4 acc[4][4] = {};

  for (int kt = 0; kt < K / 64; ++kt) {
    const int k0 = kt * 64;
#pragma unroll
    for (int i = 0; i < 4; ++i) {
      int ra = i * 32 + srow;
      GLOAD16(X + (size_t)(m0 + ra) * K + k0 + ((sch ^ (ra & 7)) << 3), smem + i * 4096 + w * 1024);
      GLOAD16(W + (size_t)(n0 + ra) * K + k0 + ((sch ^ (ra & 7)) << 3), smem + 16384 + i * 4096 + w * 1024);
    }
    __syncthreads();
#pragma unroll
    for (int kc = 0; kc < 2; ++kc) {
      bf16x8 af[4], bfr[4];
#pragma unroll
      for (int m = 0; m < 4; ++m) af[m] = ldsfrag(smem, wm * 64 + m * 16 + (l & 15), kc * 4 + (l >> 4));
#pragma unroll
      for (int n = 0; n < 4; ++n) bfr[n] = ldsfrag(smem + 16384, wn * 64 + n * 16 + (l & 15), kc * 4 + (l >> 4));
#pragma unroll
      for (int m = 0; m < 4; ++m)
#pragma unroll
        for (int n = 0; n < 4; ++n)
          acc[m][n] = mfma16(af[m], bfr[n], acc[m][n]);
    }
    __syncthreads();
  }

#pragma unroll
  for (int n = 0; n < 4; ++n) {
    float bv = bias[n0 + wn * 64 + n * 16 + (l & 15)];
#pragma unroll
    for (int m = 0; m < 4; ++m)
#pragma unroll
      for (int j = 0; j < 4; ++j)
        acc[m][n][j] = alpha * (acc[m][n][j] + bv);
  }

  float* est = (float*)(smem + w * 8704);  // per-wave epilogue staging

  if (mode == 1) {
#pragma unroll
    for (int p = 0; p < 2; ++p) {
#pragma unroll
      for (int nn = 0; nn < 2; ++nn) {
        int cl = nn * 16 + (l & 15);
#pragma unroll
        for (int m = 0; m < 4; ++m)
          *(f32x4*)(est + cl * 68 + m * 16 + ((l >> 4) << 2)) = acc[m][p * 2 + nn];
      }
#pragma unroll
      for (int i = 0; i < 8; ++i) {
        int cl = l & 31;
        int c4 = ((l >> 5) << 3) + i;
        f32x4 vv = *(const f32x4*)(est + cl * 68 + c4 * 4);
        ushort4 u;
        u.x = f2b(vv[0]); u.y = f2b(vv[1]); u.z = f2b(vv[2]); u.w = f2b(vv[3]);
        int mbase = m0 + wm * 64;
        int b = mbase >> 12;
        int s = (mbase & 4095) + c4 * 4;
        int h = (n0 + wn * 64) >> 6;
        int dh = p * 32 + cl;
        *(ushort4*)((u16*)outp + ((size_t)((b * NHEADS + h) * DHEAD + dh)) * S_LEN + s) = u;
      }
    }
  } else {
#pragma unroll
    for (int p = 0; p < 2; ++p) {
#pragma unroll
      for (int mm = 0; mm < 2; ++mm) {
#pragma unroll
        for (int n = 0; n < 4; ++n) {
          int c = n * 16 + (l & 15);
          int r0 = mm * 16 + ((l >> 4) << 2);
#pragma unroll
          for (int j = 0; j < 4; ++j)
            est[(r0 + j) * 64 + c] = acc[p * 2 + mm][n][j];
        }
      }
#pragma unroll
      for (int i = 0; i < 8; ++i) {
        int idx = i * 64 + l;
        int r = idx >> 4, c4 = idx & 15;
        f32x4 vv = *(const f32x4*)(est + r * 64 + c4 * 4);
        int mrow = m0 + wm * 64 + p * 32 + r;
        int ncol = n0 + wn * 64 + c4 * 4;
        if (mode == 2) {
          *(f32x4*)((float*)outp + (size_t)mrow * N + ncol) = vv;
        } else {
          ushort4 u;
          u.x = f2b(vv[0]); u.y = f2b(vv[1]); u.z = f2b(vv[2]); u.w = f2b(vv[3]);
          int b = mrow >> 12, s = mrow & 4095;
          int h = ncol >> 6, dh = ncol & 63;
          *(ushort4*)((u16*)outp + ((size_t)((b * NHEADS + h) * S_LEN + s)) * DHEAD + dh) = u;
        }
      }
    }
  }
}

// ------- swapped-operand flash attention, KV split-K + 1-lag pipeline -------
// 512-thread blocks, 2 groups of 4 waves; group g does KV tiles g*32..g*32+31
// for the same 128 q rows. Per interval i: stage(i+1) [SK then SV], then
// qkt(i) || smpv(i-1) (independent chains -> compiler interleaves MFMA/VALU),
// then s_waitcnt vmcnt(2) + s_barrier (leaves just-issued SV in flight).
// Buffers per group: K x2 (16KB), V x3 (24KB) = 40KB; block 80KB; 2 blocks/CU.
// Qh,Kh: [B*H][S][64] bf16 (Q pre-scaled by 0.125*log2e); Vt: [B*H][64][S].
#define FSWZ(r) (((r) ^ ((r) >> 3)) & 7)

__global__ __launch_bounds__(512) void attn_fwd(const u16* __restrict__ Qh, const u16* __restrict__ Kh,
                                                const u16* __restrict__ Vt, u16* __restrict__ O) {
  __shared__ char smem[81920];  // grp g @ g*40960: K0,K1 @0,8192; V0,V1,V2 @16384,24576,32768
  const int t = threadIdx.x, w = t >> 6, l = t & 63;
  const int grp = w >> 2, wq = w & 3;
  const int lq = l & 31, h = l >> 5;

  // bijective XCD swizzle: 512 blocks -> 64/XCD
  int id = blockIdx.y * 32 + blockIdx.x;
  int nid = (id & 7) * 64 + (id >> 3);
  const int bh = nid >> 5;
  const int q0 = (nid & 31) * 128;

  const size_t kbase = (size_t)bh * S_LEN * DHEAD;
  const size_t vbase = (size_t)bh * DHEAD * S_LEN;

  // Q fragment (B operand): q = q0 + wq*32 + lq, d = ds*16 + h*8 + j
  bf16x8 qf[4];
#pragma unroll
  for (int ds = 0; ds < 4; ++ds)
    qf[ds] = __builtin_bit_cast(bf16x8,
        *(const uint4*)(Qh + kbase + (size_t)(q0 + wq * 32 + lq) * DHEAD + ds * 16 + h * 8));

  f32x16 ot[2] = {};
  float mr = -1e30f, lr = 0.f;

  const int tl = t & 255;               // staging lane within group
  const int srow = tl >> 3, sch = tl & 7;
  const int G = grp * 40960;            // group LDS base
  const int tk0 = grp * 32;             // group's first KV tile

  // per-lane global staging base pointers (local tile j: K +4096 el, V +64 el)
  const u16* kp0 = Kh + kbase + (size_t)(tk0 * 64 + srow) * DHEAD + ((sch ^ FSWZ(srow)) << 3);
  const u16* kp1 = Kh + kbase + (size_t)(tk0 * 64 + srow + 32) * DHEAD + ((sch ^ FSWZ(srow + 32)) << 3);
  const u16* vp0 = Vt + vbase + (size_t)srow * S_LEN + tk0 * 64 + ((sch ^ FSWZ(srow)) << 3);
  const u16* vp1 = Vt + vbase + (size_t)(srow + 32) * S_LEN + tk0 * 64 + ((sch ^ FSWZ(srow + 32)) << 3);

#define SK(KOFF, j) do {                                              \
    GLOAD16(kp0 + (j) * 4096, smem + G + (KOFF) + tl * 16);           \
    GLOAD16(kp1 + (j) * 4096, smem + G + (KOFF) + 4096 + tl * 16);    \
  } while (0)
#define SV(VOFF, j) do {                                              \
    GLOAD16(vp0 + (j) * 64, smem + G + 16384 + (VOFF) + tl * 16);     \
    GLOAD16(vp1 + (j) * 64, smem + G + 16384 + (VOFF) + 4096 + tl * 16); \
  } while (0)

#define WAITBAR(n) do {                                               \
    asm volatile("s_waitcnt vmcnt(" #n ")" ::: "memory");             \
    __builtin_amdgcn_s_barrier();                                     \
  } while (0)

  // loop-invariant LDS fragment addresses: rows {lq, lq+32}, g = ds*2+h
  int addrA[4], addrB[4];
#pragma unroll
  for (int ds = 0; ds < 4; ++ds) {
    int g = ds * 2 + h;
    addrA[ds] = G + lq * 128 + ((g ^ FSWZ(lq)) << 4);
    addrB[ds] = G + (lq + 32) * 128 + ((g ^ FSWZ(lq + 32)) << 4);
  }

  auto LDF = [&](int addr) {
    return __builtin_bit_cast(bf16x8, *(const uint4*)(smem + addr));
  };

  f32x16 stA[2], stB[2];

  // S^T = K * Q^T : lane holds q=lq, k = tile*32 + (r&3)+8*(r>>2)+4*h
  auto qkt = [&](f32x16* st, int koff) {
    __builtin_amdgcn_s_setprio(1);
    {
      f32x16 zz{};
      st[0] = mfma32(LDF(addrA[0] + koff), qf[0], zz);
      st[1] = mfma32(LDF(addrB[0] + koff), qf[0], zz);
    }
#pragma unroll
    for (int ds = 1; ds < 4; ++ds) {
      st[0] = mfma32(LDF(addrA[ds] + koff), qf[ds], st[0]);
      st[1] = mfma32(LDF(addrB[ds] + koff), qf[ds], st[1]);
    }
    __builtin_amdgcn_s_setprio(0);
  };

  // online softmax + O^T += Vt * P^T ; voff in {0, 8192, 16384}
  auto smpv = [&](f32x16* st, int voff) {
    // row max over 32 in-lane values: max3 tree
    float t1[11];
#pragma unroll
    for (int i = 0; i < 10; ++i) {
      int n0i = 3 * i, n1 = 3 * i + 1, n2 = 3 * i + 2;
      t1[i] = fmax3(st[n0i >> 4][n0i & 15], st[n1 >> 4][n1 & 15], st[n2 >> 4][n2 & 15]);
    }
    t1[10] = fmaxf(st[1][14], st[1][15]);
    float t2a = fmax3(t1[0], t1[1], t1[2]);
    float t2b = fmax3(t1[3], t1[4], t1[5]);
    float t2c = fmax3(t1[6], t1[7], t1[8]);
    float t2d = fmaxf(t1[9], t1[10]);
    float mx = fmaxf(fmax3(t2a, t2b, t2c), t2d);
    {
      float xa, xb;
      xhalf(mx, xa, xb);
      mx = fmaxf(xa, xb);
    }
    if (__any(mx > mr + 8.f)) {  // defer-max (T13), exp2 domain
      float mnew = fmaxf(mr, mx);
      float f = EXP2(mr - mnew);
      lr *= f;
      ot[0] *= f;
      ot[1] *= f;
      mr = mnew;
    }
    st[0] -= mr;
    st[1] -= mr;
#pragma unroll
    for (int r = 0; r < 16; ++r) {
      st[0][r] = EXP2(st[0][r]);
      st[1][r] = EXP2(st[1][r]);
    }
    f32x16 sv = st[0] + st[1];
    f32x8 s8 = __builtin_shufflevector(sv, sv, 0, 1, 2, 3, 4, 5, 6, 7)
             + __builtin_shufflevector(sv, sv, 8, 9, 10, 11, 12, 13, 14, 15);
    f32x4 s4 = __builtin_shufflevector(s8, s8, 0, 1, 2, 3)
             + __builtin_shufflevector(s8, s8, 4, 5, 6, 7);
    float rs = (s4[0] + s4[1]) + (s4[2] + s4[3]);
    {
      float xa, xb;
      xhalf(rs, xa, xb);
      rs = xa + xb;
    }
    lr += rs;

    // P -> B-fragments in-register: cvt_pk pairs + permlane32_swap
    bf16x8 bfr[4];
#pragma unroll
    for (int ks = 0; ks < 4; ++ks) {
      int t2 = ks >> 1, base = (ks & 1) * 8;
      u32 a0 = pkbf(st[t2][base + 0], st[t2][base + 1]);
      u32 b0 = pkbf(st[t2][base + 4], st[t2][base + 5]);
      u32 a1 = pkbf(st[t2][base + 2], st[t2][base + 3]);
      u32 b1 = pkbf(st[t2][base + 6], st[t2][base + 7]);
      plswap(a0, b0);
      plswap(a1, b1);
      uint4 wv = {a0, a1, b0, b1};
      bfr[ks] = __builtin_bit_cast(bf16x8, wv);
    }
    // O^T += Vt * P^T
    __builtin_amdgcn_s_setprio(1);
#pragma unroll
    for (int ks = 0; ks < 4; ++ks) {
      ot[0] = mfma32(LDF(addrA[ks] + 16384 + voff), bfr[ks], ot[0]);
      ot[1] = mfma32(LDF(addrB[ks] + 16384 + voff), bfr[ks], ot[1]);
    }
    __builtin_amdgcn_s_setprio(0);
  };

  // ---- prologue: establish steady state (entry of interval 1) ----
  SK(0, 0); SV(0, 0); SK(8192, 1);
  WAITBAR(2);            // K(0), V(0) landed; SK(1) in flight
  SV(8192, 1);
  qkt(stA, 0);           // interval 0 (no smpv)
  WAITBAR(2);            // K(1) landed; SV(1) in flight

  // ---- steady intervals 1..30, 6-unrolled (K parity x V mod-3) ----
  for (int m6 = 0; m6 < 5; ++m6) {
    const int base = 6 * m6;
    SK(0, base + 2);    SV(16384, base + 2);
    qkt(stB, 8192);     smpv(stA, 0);      WAITBAR(2);
    SK(8192, base + 3); SV(0, base + 3);
    qkt(stA, 0);        smpv(stB, 8192);   WAITBAR(2);
    SK(0, base + 4);    SV(8192, base + 4);
    qkt(stB, 8192);     smpv(stA, 16384);  WAITBAR(2);
    SK(8192, base + 5); SV(16384, base + 5);
    qkt(stA, 0);        smpv(stB, 0);      WAITBAR(2);
    SK(0, base + 6);    SV(0, base + 6);
    qkt(stB, 8192);     smpv(stA, 8192);   WAITBAR(2);
    SK(8192, base + 7); SV(8192, base + 7);
    qkt(stA, 0);        smpv(stB, 16384);  WAITBAR(2);
  }

  // ---- interval 31 + final smpv ----
  qkt(stB, 8192);  smpv(stA, 0);   // K(31)@K1, V(30)@V0
  WAITBAR(0);                      // V(31) landed everywhere
  smpv(stB, 8192);                 // V(31)@V1

  // ---- split-K merge: group1 -> slots @smem[0..36864), group0 merges ----
  __syncthreads();
  if (grp == 1) {
    float* slot = (float*)smem + (wq * 64 + l) * 36;
#pragma unroll
    for (int dt = 0; dt < 2; ++dt)
#pragma unroll
      for (int r = 0; r < 16; ++r) slot[dt * 16 + r] = ot[dt][r];
    slot[32] = mr;
    slot[33] = lr;
  }
  __syncthreads();
  if (grp == 0) {
    const float* slot = (const float*)smem + (wq * 64 + l) * 36;
    float m1 = slot[32], l1 = slot[33];
    float mf = fmaxf(mr, m1);
    float fa = EXP2(mr - mf), fb = EXP2(m1 - mf);
    float inv = 1.0f / (lr * fa + l1 * fb);
    fa *= inv;
    fb *= inv;
    // normalize+merge, stage per-wave [32 q][64 d] bf16 @ 40960 + wq*4096
    char* Ow = smem + 40960 + wq * 4096;
#pragma unroll
    for (int dt = 0; dt < 2; ++dt)
#pragma unroll
      for (int c = 0; c < 4; ++c) {
        float e0 = ot[dt][c * 4 + 0] * fa + slot[dt * 16 + c * 4 + 0] * fb;
        float e1 = ot[dt][c * 4 + 1] * fa + slot[dt * 16 + c * 4 + 1] * fb;
        float e2 = ot[dt][c * 4 + 2] * fa + slot[dt * 16 + c * 4 + 2] * fb;
        float e3 = ot[dt][c * 4 + 3] * fa + slot[dt * 16 + c * 4 + 3] * fb;
        u32 u0 = pkbf(e0, e1);
        u32 u1 = pkbf(e2, e3);
        int pidx = dt * 4 + c;  // d = pidx*8 + h*4 + {0..3}
        unsigned long long pp = (unsigned long long)u0 | ((unsigned long long)u1 << 32);
        *(unsigned long long*)(Ow + lq * 128 + ((pidx ^ (lq & 7)) << 4) + h * 8) = pp;
      }
  }
  __syncthreads();
  if (t < 256) {
    const int b = bh >> 3, hh = bh & 7;
#pragma unroll
    for (int it = 0; it < 4; ++it) {
      int idx = it * 256 + t;
      int row = idx >> 3, g = idx & 7;
      uint4 vv = *(const uint4*)(smem + 40960 + (row >> 5) * 4096 + (row & 31) * 128 + ((g ^ (row & 7)) << 4));
      *(uint4*)(O + ((size_t)b * S_LEN + q0 + row) * DMODEL + hh * DHEAD + g * 8) = vv;
    }
  }
#undef SK
#undef SV
#undef WAITBAR
}

extern "C" void kernel_launch(void* const* d_in, const int* in_sizes, int n_in,
                              void* d_out, int out_size, void* d_ws, size_t ws_size,
                              hipStream_t stream) {
  const float* q  = (const float*)d_in[0];
  const float* k  = (const float*)d_in[1];
  const float* v  = (const float*)d_in[2];
  const float* Wq = (const float*)d_in[3];
  const float* bq = (const float*)d_in[4];
  const float* Wk = (const float*)d_in[5];
  const float* bk = (const float*)d_in[6];
  const float* Wv = (const float*)d_in[7];
  const float* bv = (const float*)d_in[8];
  const float* Wo = (const float*)d_in[9];
  const float* bo = (const float*)d_in[10];

  char* ws = (char*)d_ws;
  u16* wqb = (u16*)ws;                 // 4 x 512KB bf16 weight buffers
  u16* wkb = wqb + 262144;
  u16* wvb = wkb + 262144;
  u16* wob = wvb + 262144;

  const float SCALE = 0.125f * 1.4426950408889634f;  // 1/sqrt(64) * log2(e)
  const size_t XSZ = (size_t)8192 * 512 * 2;         // bf16 [8192,512] = 8388608 B
  const size_t FUSED_NEED = 2097152 + 6 * XSZ;       // 54,525,952 B

  // fused weight convert (1 launch)
  cvt_w4<<<1024, 256, 0, stream>>>(Wq, Wk, Wv, Wo, wqb, wkb, wvb, wob);

  if (ws_size >= FUSED_NEED) {
    // ---- fused path: 5 launches total ----
    u16* Xq = (u16*)(ws + 2097152);
    u16* Xk = (u16*)(ws + 2097152 + XSZ);
    u16* Xv = (u16*)(ws + 2097152 + 2 * XSZ);
    u16* Qh = (u16*)(ws + 2097152 + 3 * XSZ);
    u16* Kb = (u16*)(ws + 2097152 + 4 * XSZ);
    u16* Vb = (u16*)(ws + 2097152 + 5 * XSZ);
    u16* AttnO = Xq;  // alias: X buffers dead once gemm_qkv completes

    cvt_in3<<<12288, 256, 0, stream>>>(q, k, v, Xq, Xk, Xv);

    gemm_xwt<<<dim3(4, 64, 3), 256, 0, stream>>>(
        Xq, Xk, Xv, wqb, wkb, wvb, bq, bk, bv, Qh, Kb, Vb,
        SCALE, 1.0f, 1.0f, -1);

    attn_fwd<<<dim3(32, 16), 512, 0, stream>>>(Qh, Kb, Vb, AttnO);

    gemm_xwt<<<dim3(4, 64, 1), 256, 0, stream>>>(
        AttnO, AttnO, AttnO, wob, wob, wob, bo, bo, bo, d_out, d_out, d_out,
        1.0f, 1.0f, 1.0f, 2);
  } else {
    // ---- fallback: sequential path ----
    u16* R0 = (u16*)(ws + 2097152);
    u16* Qh = (u16*)(ws + 2097152 + XSZ);
    u16* Kb = (u16*)(ws + 2097152 + 2 * XSZ);
    u16* Vb = (u16*)(ws + 2097152 + 3 * XSZ);

    cvt4<<<4096, 256, 0, stream>>>(q, R0, 1048576);
    gemm_xwt<<<dim3(4, 64, 1), 256, 0, stream>>>(
        R0, R0, R0, wqb, wqb, wqb, bq, bq, bq, Qh, Qh, Qh, SCALE, SCALE, SCALE, 0);
    cvt4<<<4096, 256, 0, stream>>>(k, R0, 1048576);
    gemm_xwt<<<dim3(4, 64, 1), 256, 0, stream>>>(
        R0, R0, R0, wkb, wkb, wkb, bk, bk, bk, Kb, Kb, Kb, 1.0f, 1.0f, 1.0f, 0);
    cvt4<<<4096, 256, 0, stream>>>(v, R0, 1048576);
    gemm_xwt<<<dim3(4, 64, 1), 256, 0, stream>>>(
        R0, R0, R0, wvb, wvb, wvb, bv, bv, bv, Vb, Vb, Vb, 1.0f, 1.0f, 1.0f, 1);

    attn_fwd<<<dim3(32, 16), 512, 0, stream>>>(Qh, Kb, Vb, R0);

    gemm_xwt<<<dim3(4, 64, 1), 256, 0, stream>>>(
        R0, R0, R0, wob, wob, wob, bo, bo, bo, d_out, d_out, d_out,
        1.0f, 1.0f, 1.0f, 2);
  }
}

// Round 9
// 145.920 us; speedup vs baseline: 1.0442x; 1.0442x over previous
//
#include <hip/hip_runtime.h>

#define S_LEN 4096
#define DMODEL 512
#define NHEADS 8
#define DHEAD 64

typedef unsigned short u16;
typedef unsigned int u32;
typedef __attribute__((ext_vector_type(8))) short bf16x8;
typedef __attribute__((ext_vector_type(4))) float f32x4;
typedef __attribute__((ext_vector_type(8))) float f32x8;
typedef __attribute__((ext_vector_type(16))) float f32x16;

#if __has_builtin(__builtin_amdgcn_exp2f)
#define EXP2(x) __builtin_amdgcn_exp2f(x)
#else
#define EXP2(x) exp2f(x)
#endif

__device__ __forceinline__ u16 f2b(float f) {
  unsigned u = __builtin_bit_cast(unsigned, f);
  return (u16)((u + 0x7fffu + ((u >> 16) & 1u)) >> 16);
}
__device__ __forceinline__ float fmax3(float a, float b, float c) {
  return fmaxf(fmaxf(a, b), c);
}

__device__ __forceinline__ f32x4 mfma16(bf16x8 a, bf16x8 b, f32x4 c) {
  return __builtin_amdgcn_mfma_f32_16x16x32_bf16(a, b, c, 0, 0, 0);
}
__device__ __forceinline__ f32x16 mfma32(bf16x8 a, bf16x8 b, f32x16 c) {
  return __builtin_amdgcn_mfma_f32_32x32x16_bf16(a, b, c, 0, 0, 0);
}

// pack two f32 -> one u32 of 2 bf16 (RNE), S0 -> low half
__device__ __forceinline__ u32 pkbf(float lo, float hi) {
  u32 r;
  asm("v_cvt_pk_bf16_f32 %0, %1, %2" : "=v"(r) : "v"(lo), "v"(hi));
  return r;
}

// swap a.hi32lanes <-> b.lo32lanes
__device__ __forceinline__ void plswap(u32& a, u32& b) {
#if __has_builtin(__builtin_amdgcn_permlane32_swap)
  auto r = __builtin_amdgcn_permlane32_swap(a, b, false, false);
  a = r[0];
  b = r[1];
#else
  u32 as = __shfl_xor((int)a, 32), bs = __shfl_xor((int)b, 32);
  bool hi = (threadIdx.x & 32) != 0;
  u32 na = hi ? bs : a;
  u32 nb = hi ? b : as;
  a = na;
  b = nb;
#endif
}
// cross-half (lane ^ 32) exchange of one value, both outputs
__device__ __forceinline__ void xhalf(float x, float& own, float& other) {
  u32 a = __builtin_bit_cast(u32, x), b = a;
  plswap(a, b);
  own = __builtin_bit_cast(float, a);
  other = __builtin_bit_cast(float, b);
}

// read a 16B MFMA fragment from an LDS tile with 128B rows, XOR chunk swizzle
__device__ __forceinline__ bf16x8 ldsfrag(const char* base, int row, int chunk) {
  chunk ^= (row & 7);
  return __builtin_bit_cast(bf16x8, *(const uint4*)(base + row * 128 + chunk * 16));
}

#define GLOAD16(gsrc, ldst) __builtin_amdgcn_global_load_lds( \
    (const __attribute__((address_space(1))) void*)(gsrc),    \
    (__attribute__((address_space(3))) void*)(ldst), 16, 0, 0)

// fp32 -> bf16: all 7 tensors (4 weights @65536 f4 each, 3 inputs @1048576 f4
// each) in ONE launch. blocks 0..1023 -> weights, 1024..13311 -> inputs.
__global__ void cvt_all(const float* __restrict__ wa, const float* __restrict__ wb,
                        const float* __restrict__ wc, const float* __restrict__ wd,
                        const float* __restrict__ ia, const float* __restrict__ ib,
                        const float* __restrict__ ic,
                        u16* __restrict__ owa, u16* __restrict__ owb,
                        u16* __restrict__ owc, u16* __restrict__ owd,
                        u16* __restrict__ oia, u16* __restrict__ oib,
                        u16* __restrict__ oic) {
  int bid = blockIdx.x;
  const float* src;
  u16* dst;
  int i;
  if (bid < 1024) {
    int which = bid >> 8;
    i = (bid & 255) * 256 + threadIdx.x;
    src = which == 0 ? wa : which == 1 ? wb : which == 2 ? wc : wd;
    dst = which == 0 ? owa : which == 1 ? owb : which == 2 ? owc : owd;
  } else {
    bid -= 1024;
    int which = bid >> 12;
    i = (bid & 4095) * 256 + threadIdx.x;
    src = which == 0 ? ia : which == 1 ? ib : ic;
    dst = which == 0 ? oia : which == 1 ? oib : oic;
  }
  float4 v = ((const float4*)src)[i];
  ushort4 o;
  o.x = f2b(v.x); o.y = f2b(v.y); o.z = f2b(v.z); o.w = f2b(v.w);
  ((ushort4*)dst)[i] = o;
}

// single fp32->bf16 (fallback path)
__global__ void cvt4(const float* __restrict__ in, u16* __restrict__ out, int n4) {
  int i = blockIdx.x * blockDim.x + threadIdx.x;
  if (i < n4) {
    float4 v = ((const float4*)in)[i];
    ushort4 o;
    o.x = f2b(v.x); o.y = f2b(v.y); o.z = f2b(v.z); o.w = f2b(v.w);
    ((ushort4*)out)[i] = o;
  }
}

// C = alpha * (X[M,K] @ W[N,K]^T + bias[N]);  X,W bf16, acc fp32.
// mode 0: bf16 out[((b*H+h)*S + s)*64 + dh]      (m=b*4096+s, n=h*64+dh)
// mode 1: bf16 out[((b*H+h)*64 + dh)*S + s]      (V transposed)
// mode 2: f32  out[m*N + n]
// blockIdx.z selects (X,W,bias,out,alpha); modesel==-1: mode = (z==2)?1:0,
// else mode = modesel.
__global__ __launch_bounds__(256) void gemm_xwt(
    const u16* __restrict__ X0, const u16* __restrict__ X1, const u16* __restrict__ X2,
    const u16* __restrict__ W0, const u16* __restrict__ W1, const u16* __restrict__ W2,
    const float* __restrict__ b0, const float* __restrict__ b1, const float* __restrict__ b2,
    void* __restrict__ o0, void* __restrict__ o1, void* __restrict__ o2,
    float alpha0, float alpha1, float alpha2, int modesel) {
  constexpr int K = 512, N = 512;
  __shared__ char smem[34816];
  const int z = blockIdx.z;
  const u16* X = z == 0 ? X0 : z == 1 ? X1 : X2;
  const u16* W = z == 0 ? W0 : z == 1 ? W1 : W2;
  const float* bias = z == 0 ? b0 : z == 1 ? b1 : b2;
  void* outp = z == 0 ? o0 : z == 1 ? o1 : o2;
  const float alpha = z == 0 ? alpha0 : z == 1 ? alpha1 : alpha2;
  const int mode = modesel >= 0 ? modesel : (z == 2 ? 1 : 0);

  const int t = threadIdx.x;
  const int w = t >> 6, l = t & 63;
  const int wm = w >> 1, wn = w & 1;
  const int m0 = blockIdx.y * 128, n0 = blockIdx.x * 128;
  const int srow = t >> 3, sch = t & 7;

  f32x4 acc[4][4] = {};

  for (int kt = 0; kt < K / 64; ++kt) {
    const int k0 = kt * 64;
#pragma unroll
    for (int i = 0; i < 4; ++i) {
      int ra = i * 32 + srow;
      GLOAD16(X + (size_t)(m0 + ra) * K + k0 + ((sch ^ (ra & 7)) << 3), smem + i * 4096 + w * 1024);
      GLOAD16(W + (size_t)(n0 + ra) * K + k0 + ((sch ^ (ra & 7)) << 3), smem + 16384 + i * 4096 + w * 1024);
    }
    __syncthreads();
#pragma unroll
    for (int kc = 0; kc < 2; ++kc) {
      bf16x8 af[4], bfr[4];
#pragma unroll
      for (int m = 0; m < 4; ++m) af[m] = ldsfrag(smem, wm * 64 + m * 16 + (l & 15), kc * 4 + (l >> 4));
#pragma unroll
      for (int n = 0; n < 4; ++n) bfr[n] = ldsfrag(smem + 16384, wn * 64 + n * 16 + (l & 15), kc * 4 + (l >> 4));
#pragma unroll
      for (int m = 0; m < 4; ++m)
#pragma unroll
        for (int n = 0; n < 4; ++n)
          acc[m][n] = mfma16(af[m], bfr[n], acc[m][n]);
    }
    __syncthreads();
  }

#pragma unroll
  for (int n = 0; n < 4; ++n) {
    float bv = bias[n0 + wn * 64 + n * 16 + (l & 15)];
#pragma unroll
    for (int m = 0; m < 4; ++m)
#pragma unroll
      for (int j = 0; j < 4; ++j)
        acc[m][n][j] = alpha * (acc[m][n][j] + bv);
  }

  float* est = (float*)(smem + w * 8704);  // per-wave epilogue staging

  if (mode == 1) {
#pragma unroll
    for (int p = 0; p < 2; ++p) {
#pragma unroll
      for (int nn = 0; nn < 2; ++nn) {
        int cl = nn * 16 + (l & 15);
#pragma unroll
        for (int m = 0; m < 4; ++m)
          *(f32x4*)(est + cl * 68 + m * 16 + ((l >> 4) << 2)) = acc[m][p * 2 + nn];
      }
#pragma unroll
      for (int i = 0; i < 8; ++i) {
        int cl = l & 31;
        int c4 = ((l >> 5) << 3) + i;
        f32x4 vv = *(const f32x4*)(est + cl * 68 + c4 * 4);
        ushort4 u;
        u.x = f2b(vv[0]); u.y = f2b(vv[1]); u.z = f2b(vv[2]); u.w = f2b(vv[3]);
        int mbase = m0 + wm * 64;
        int b = mbase >> 12;
        int s = (mbase & 4095) + c4 * 4;
        int h = (n0 + wn * 64) >> 6;
        int dh = p * 32 + cl;
        *(ushort4*)((u16*)outp + ((size_t)((b * NHEADS + h) * DHEAD + dh)) * S_LEN + s) = u;
      }
    }
  } else {
#pragma unroll
    for (int p = 0; p < 2; ++p) {
#pragma unroll
      for (int mm = 0; mm < 2; ++mm) {
#pragma unroll
        for (int n = 0; n < 4; ++n) {
          int c = n * 16 + (l & 15);
          int r0 = mm * 16 + ((l >> 4) << 2);
#pragma unroll
          for (int j = 0; j < 4; ++j)
            est[(r0 + j) * 64 + c] = acc[p * 2 + mm][n][j];
        }
      }
#pragma unroll
      for (int i = 0; i < 8; ++i) {
        int idx = i * 64 + l;
        int r = idx >> 4, c4 = idx & 15;
        f32x4 vv = *(const f32x4*)(est + r * 64 + c4 * 4);
        int mrow = m0 + wm * 64 + p * 32 + r;
        int ncol = n0 + wn * 64 + c4 * 4;
        if (mode == 2) {
          *(f32x4*)((float*)outp + (size_t)mrow * N + ncol) = vv;
        } else {
          ushort4 u;
          u.x = f2b(vv[0]); u.y = f2b(vv[1]); u.z = f2b(vv[2]); u.w = f2b(vv[3]);
          int b = mrow >> 12, s = mrow & 4095;
          int h = ncol >> 6, dh = ncol & 63;
          *(ushort4*)((u16*)outp + ((size_t)((b * NHEADS + h) * S_LEN + s)) * DHEAD + dh) = u;
        }
      }
    }
  }
}

// ---------------- swapped-operand flash attention, KV split-K ----------------
// (R7 version — best measured: 110 us, VGPR 72.) 512-thread blocks: group 0
// (waves 0-3) does KV tiles 0..31, group 1 does 32..63, same 128 q rows,
// private (m,l,O) + private double-buffered K/V LDS. End: lane-aligned merge.
// Qh,Kh: [B*H][S][64] bf16 (Q pre-scaled by 0.125*log2e); Vt: [B*H][64][S].
#define FSWZ(r) (((r) ^ ((r) >> 3)) & 7)

__global__ __launch_bounds__(512) void attn_fwd(const u16* __restrict__ Qh, const u16* __restrict__ Kh,
                                                const u16* __restrict__ Vt, u16* __restrict__ O) {
  __shared__ char smem[65536];  // grp g: K[2][64][64] @ g*32768, V[2][64][64] @ g*32768+16384
  const int t = threadIdx.x, w = t >> 6, l = t & 63;
  const int grp = w >> 2, wq = w & 3;
  const int lq = l & 31, h = l >> 5;

  // bijective XCD swizzle: 512 blocks -> 64/XCD
  int id = blockIdx.y * 32 + blockIdx.x;
  int nid = (id & 7) * 64 + (id >> 3);
  const int bh = nid >> 5;
  const int q0 = (nid & 31) * 128;

  const size_t kbase = (size_t)bh * S_LEN * DHEAD;
  const size_t vbase = (size_t)bh * DHEAD * S_LEN;

  // Q fragment (B operand): q = q0 + wq*32 + lq, d = ds*16 + h*8 + j
  bf16x8 qf[4];
#pragma unroll
  for (int ds = 0; ds < 4; ++ds)
    qf[ds] = __builtin_bit_cast(bf16x8,
        *(const uint4*)(Qh + kbase + (size_t)(q0 + wq * 32 + lq) * DHEAD + ds * 16 + h * 8));

  f32x16 ot[2] = {};
  float mr = -1e30f, lr = 0.f;

  const int tl = t & 255;               // staging lane within group
  const int srow = tl >> 3, sch = tl & 7;
  const int G = grp * 32768;            // group LDS base
  const int tk0 = grp * 32;             // group's first KV tile

  // per-lane global staging base pointers (local tile j: K +4096 el, V +64 el)
  const u16* kp0 = Kh + kbase + (size_t)(tk0 * 64 + srow) * DHEAD + ((sch ^ FSWZ(srow)) << 3);
  const u16* kp1 = Kh + kbase + (size_t)(tk0 * 64 + srow + 32) * DHEAD + ((sch ^ FSWZ(srow + 32)) << 3);
  const u16* vp0 = Vt + vbase + (size_t)srow * S_LEN + tk0 * 64 + ((sch ^ FSWZ(srow)) << 3);
  const u16* vp1 = Vt + vbase + (size_t)(srow + 32) * S_LEN + tk0 * 64 + ((sch ^ FSWZ(srow + 32)) << 3);

#define SK(KOFF, j) do {                                              \
    GLOAD16(kp0 + (j) * 4096, smem + G + (KOFF) + tl * 16);           \
    GLOAD16(kp1 + (j) * 4096, smem + G + (KOFF) + 4096 + tl * 16);    \
  } while (0)
#define SV(VOFF, j) do {                                              \
    GLOAD16(vp0 + (j) * 64, smem + G + 16384 + (VOFF) + tl * 16);     \
    GLOAD16(vp1 + (j) * 64, smem + G + 16384 + (VOFF) + 4096 + tl * 16); \
  } while (0)

#define WAITBAR(n) do {                                               \
    asm volatile("s_waitcnt vmcnt(" #n ")" ::: "memory");             \
    __builtin_amdgcn_s_barrier();                                     \
  } while (0)

  // loop-invariant LDS fragment addresses: rows {lq, lq+32}, g = ds*2+h
  int addrA[4], addrB[4];
#pragma unroll
  for (int ds = 0; ds < 4; ++ds) {
    int g = ds * 2 + h;
    addrA[ds] = G + lq * 128 + ((g ^ FSWZ(lq)) << 4);
    addrB[ds] = G + (lq + 32) * 128 + ((g ^ FSWZ(lq + 32)) << 4);
  }

  auto LDF = [&](int addr) {
    return __builtin_bit_cast(bf16x8, *(const uint4*)(smem + addr));
  };

  f32x16 st[2];

  // S^T = K * Q^T : lane holds q=lq, k = tile*32 + (r&3)+8*(r>>2)+4*h
  auto qkt = [&](int koff) {
    __builtin_amdgcn_s_setprio(1);
    {
      f32x16 zz{};
      st[0] = mfma32(LDF(addrA[0] + koff), qf[0], zz);
      st[1] = mfma32(LDF(addrB[0] + koff), qf[0], zz);
    }
#pragma unroll
    for (int ds = 1; ds < 4; ++ds) {
      st[0] = mfma32(LDF(addrA[ds] + koff), qf[ds], st[0]);
      st[1] = mfma32(LDF(addrB[ds] + koff), qf[ds], st[1]);
    }
    __builtin_amdgcn_s_setprio(0);
  };

  // online softmax + O^T += Vt * P^T ; voff in {0, 8192}
  auto smpv = [&](int voff) {
    // row max over 32 in-lane values: max3 tree
    float t1[11];
#pragma unroll
    for (int i = 0; i < 10; ++i) {
      int n0i = 3 * i, n1 = 3 * i + 1, n2 = 3 * i + 2;
      t1[i] = fmax3(st[n0i >> 4][n0i & 15], st[n1 >> 4][n1 & 15], st[n2 >> 4][n2 & 15]);
    }
    t1[10] = fmaxf(st[1][14], st[1][15]);
    float t2a = fmax3(t1[0], t1[1], t1[2]);
    float t2b = fmax3(t1[3], t1[4], t1[5]);
    float t2c = fmax3(t1[6], t1[7], t1[8]);
    float t2d = fmaxf(t1[9], t1[10]);
    float mx = fmaxf(fmax3(t2a, t2b, t2c), t2d);
    {
      float xa, xb;
      xhalf(mx, xa, xb);
      mx = fmaxf(xa, xb);
    }
    if (__any(mx > mr + 8.f)) {  // defer-max (T13), exp2 domain
      float mnew = fmaxf(mr, mx);
      float f = EXP2(mr - mnew);
      lr *= f;
      ot[0] *= f;
      ot[1] *= f;
      mr = mnew;
    }
    st[0] -= mr;
    st[1] -= mr;
#pragma unroll
    for (int r = 0; r < 16; ++r) {
      st[0][r] = EXP2(st[0][r]);
      st[1][r] = EXP2(st[1][r]);
    }
    f32x16 sv = st[0] + st[1];
    f32x8 s8 = __builtin_shufflevector(sv, sv, 0, 1, 2, 3, 4, 5, 6, 7)
             + __builtin_shufflevector(sv, sv, 8, 9, 10, 11, 12, 13, 14, 15);
    f32x4 s4 = __builtin_shufflevector(s8, s8, 0, 1, 2, 3)
             + __builtin_shufflevector(s8, s8, 4, 5, 6, 7);
    float rs = (s4[0] + s4[1]) + (s4[2] + s4[3]);
    {
      float xa, xb;
      xhalf(rs, xa, xb);
      rs = xa + xb;
    }
    lr += rs;

    // P -> B-fragments in-register: cvt_pk pairs + permlane32_swap
    bf16x8 bfr[4];
#pragma unroll
    for (int ks = 0; ks < 4; ++ks) {
      int t2 = ks >> 1, base = (ks & 1) * 8;
      u32 a0 = pkbf(st[t2][base + 0], st[t2][base + 1]);
      u32 b0 = pkbf(st[t2][base + 4], st[t2][base + 5]);
      u32 a1 = pkbf(st[t2][base + 2], st[t2][base + 3]);
      u32 b1 = pkbf(st[t2][base + 6], st[t2][base + 7]);
      plswap(a0, b0);
      plswap(a1, b1);
      uint4 wv = {a0, a1, b0, b1};
      bfr[ks] = __builtin_bit_cast(bf16x8, wv);
    }
    // O^T += Vt * P^T
    __builtin_amdgcn_s_setprio(1);
#pragma unroll
    for (int ks = 0; ks < 4; ++ks) {
      ot[0] = mfma32(LDF(addrA[ks] + 16384 + voff), bfr[ks], ot[0]);
      ot[1] = mfma32(LDF(addrB[ks] + 16384 + voff), bfr[ks], ot[1]);
    }
    __builtin_amdgcn_s_setprio(0);
  };

  // ---- pipeline: 2-deep; iter j computes buf j&1, stages j+1 into (j+1)&1 ----
  SK(0, 0); SV(0, 0);
  for (int m5 = 0; m5 < 15; ++m5) {
    const int j = 2 * m5;
    SK(8192, j + 1); SV(8192, j + 1);
    WAITBAR(4);
    qkt(0);    smpv(0);
    SK(0, j + 2); SV(0, j + 2);
    WAITBAR(4);
    qkt(8192); smpv(8192);
  }
  // j=30
  SK(8192, 31); SV(8192, 31);
  WAITBAR(4);
  qkt(0); smpv(0);
  // j=31
  WAITBAR(0);
  qkt(8192); smpv(8192);

  // ---- split-K merge: group1 -> LDS slots @16384, group0 merges ----
  __syncthreads();
  if (grp == 1) {
    float* slot = (float*)(smem + 16384) + (wq * 64 + l) * 36;
#pragma unroll
    for (int dt = 0; dt < 2; ++dt)
#pragma unroll
      for (int r = 0; r < 16; ++r) slot[dt * 16 + r] = ot[dt][r];
    slot[32] = mr;
    slot[33] = lr;
  }
  __syncthreads();
  if (grp == 0) {
    const float* slot = (const float*)(smem + 16384) + (wq * 64 + l) * 36;
    float m1 = slot[32], l1 = slot[33];
    float mf = fmaxf(mr, m1);
    float fa = EXP2(mr - mf), fb = EXP2(m1 - mf);
    float inv = 1.0f / (lr * fa + l1 * fb);
    fa *= inv;
    fb *= inv;
    // normalize+merge, stage per-wave [32 q][64 d] bf16 @ wq*4096 (0..16KB)
    char* Ow = smem + wq * 4096;
#pragma unroll
    for (int dt = 0; dt < 2; ++dt)
#pragma unroll
      for (int c = 0; c < 4; ++c) {
        float e0 = ot[dt][c * 4 + 0] * fa + slot[dt * 16 + c * 4 + 0] * fb;
        float e1 = ot[dt][c * 4 + 1] * fa + slot[dt * 16 + c * 4 + 1] * fb;
        float e2 = ot[dt][c * 4 + 2] * fa + slot[dt * 16 + c * 4 + 2] * fb;
        float e3 = ot[dt][c * 4 + 3] * fa + slot[dt * 16 + c * 4 + 3] * fb;
        u32 u0 = pkbf(e0, e1);
        u32 u1 = pkbf(e2, e3);
        int pidx = dt * 4 + c;  // d = pidx*8 + h*4 + {0..3}
        unsigned long long pp = (unsigned long long)u0 | ((unsigned long long)u1 << 32);
        *(unsigned long long*)(Ow + lq * 128 + ((pidx ^ (lq & 7)) << 4) + h * 8) = pp;
      }
  }
  __syncthreads();
  if (t < 256) {
    const int b = bh >> 3, hh = bh & 7;
#pragma unroll
    for (int it = 0; it < 4; ++it) {
      int idx = it * 256 + t;
      int row = idx >> 3, g = idx & 7;
      uint4 vv = *(const uint4*)(smem + (row >> 5) * 4096 + (row & 31) * 128 + ((g ^ (row & 7)) << 4));
      *(uint4*)(O + ((size_t)b * S_LEN + q0 + row) * DMODEL + hh * DHEAD + g * 8) = vv;
    }
  }
#undef SK
#undef SV
#undef WAITBAR
}

extern "C" void kernel_launch(void* const* d_in, const int* in_sizes, int n_in,
                              void* d_out, int out_size, void* d_ws, size_t ws_size,
                              hipStream_t stream) {
  const float* q  = (const float*)d_in[0];
  const float* k  = (const float*)d_in[1];
  const float* v  = (const float*)d_in[2];
  const float* Wq = (const float*)d_in[3];
  const float* bq = (const float*)d_in[4];
  const float* Wk = (const float*)d_in[5];
  const float* bk = (const float*)d_in[6];
  const float* Wv = (const float*)d_in[7];
  const float* bv = (const float*)d_in[8];
  const float* Wo = (const float*)d_in[9];
  const float* bo = (const float*)d_in[10];

  char* ws = (char*)d_ws;
  u16* wqb = (u16*)ws;                 // 4 x 512KB bf16 weight buffers
  u16* wkb = wqb + 262144;
  u16* wvb = wkb + 262144;
  u16* wob = wvb + 262144;

  const float SCALE = 0.125f * 1.4426950408889634f;  // 1/sqrt(64) * log2(e)
  const size_t XSZ = (size_t)8192 * 512 * 2;         // bf16 [8192,512] = 8388608 B
  const size_t FUSED_NEED = 2097152 + 6 * XSZ;       // 54,525,952 B

  if (ws_size >= FUSED_NEED) {
    // ---- fused path: 4 launches total ----
    u16* Xq = (u16*)(ws + 2097152);
    u16* Xk = (u16*)(ws + 2097152 + XSZ);
    u16* Xv = (u16*)(ws + 2097152 + 2 * XSZ);
    u16* Qh = (u16*)(ws + 2097152 + 3 * XSZ);
    u16* Kb = (u16*)(ws + 2097152 + 4 * XSZ);
    u16* Vb = (u16*)(ws + 2097152 + 5 * XSZ);
    u16* AttnO = Xq;  // alias: X buffers dead once gemm_qkv completes

    cvt_all<<<13312, 256, 0, stream>>>(Wq, Wk, Wv, Wo, q, k, v,
                                       wqb, wkb, wvb, wob, Xq, Xk, Xv);

    gemm_xwt<<<dim3(4, 64, 3), 256, 0, stream>>>(
        Xq, Xk, Xv, wqb, wkb, wvb, bq, bk, bv, Qh, Kb, Vb,
        SCALE, 1.0f, 1.0f, -1);

    attn_fwd<<<dim3(32, 16), 512, 0, stream>>>(Qh, Kb, Vb, AttnO);

    gemm_xwt<<<dim3(4, 64, 1), 256, 0, stream>>>(
        AttnO, AttnO, AttnO, wob, wob, wob, bo, bo, bo, d_out, d_out, d_out,
        1.0f, 1.0f, 1.0f, 2);
  } else {
    // ---- fallback: sequential path ----
    u16* R0 = (u16*)(ws + 2097152);
    u16* Qh = (u16*)(ws + 2097152 + XSZ);
    u16* Kb = (u16*)(ws + 2097152 + 2 * XSZ);
    u16* Vb = (u16*)(ws + 2097152 + 3 * XSZ);

    cvt4<<<256, 256, 0, stream>>>(Wq, wqb, 65536);
    cvt4<<<256, 256, 0, stream>>>(Wk, wkb, 65536);
    cvt4<<<256, 256, 0, stream>>>(Wv, wvb, 65536);
    cvt4<<<256, 256, 0, stream>>>(Wo, wob, 65536);

    cvt4<<<4096, 256, 0, stream>>>(q, R0, 1048576);
    gemm_xwt<<<dim3(4, 64, 1), 256, 0, stream>>>(
        R0, R0, R0, wqb, wqb, wqb, bq, bq, bq, Qh, Qh, Qh, SCALE, SCALE, SCALE, 0);
    cvt4<<<4096, 256, 0, stream>>>(k, R0, 1048576);
    gemm_xwt<<<dim3(4, 64, 1), 256, 0, stream>>>(
        R0, R0, R0, wkb, wkb, wkb, bk, bk, bk, Kb, Kb, Kb, 1.0f, 1.0f, 1.0f, 0);
    cvt4<<<4096, 256, 0, stream>>>(v, R0, 1048576);
    gemm_xwt<<<dim3(4, 64, 1), 256, 0, stream>>>(
        R0, R0, R0, wvb, wvb, wvb, bv, bv, bv, Vb, Vb, Vb, 1.0f, 1.0f, 1.0f, 1);

    attn_fwd<<<dim3(32, 16), 512, 0, stream>>>(Qh, Kb, Vb, R0);

    gemm_xwt<<<dim3(4, 64, 1), 256, 0, stream>>>(
        R0, R0, R0, wob, wob, wob, bo, bo, bo, d_out, d_out, d_out,
        1.0f, 1.0f, 1.0f, 2);
  }
}